// Round 5
// baseline (556.274 us; speedup 1.0000x reference)
//
#include <hip/hip_runtime.h>
#include <cstdint>
#include <cstddef>

#define BB 8
#define SS 1024
#define HH 768
#define TT 8
#define DII 64
#define HIDD 128
#define KSP 8
#define NHEADS 2
#define NNODES 9
#define GDIM 256   // NHEADS*HIDD
#define CDIM 1024  // TT*2*DII == HH+GDIM
#define DAUGP 96   // 64 rope + 16 gauss + 16 zero pad (3 x 32-k MFMA slabs)
#define NEGV 1e12f

using bf16x8 = __attribute__((ext_vector_type(8))) __bf16;
using f32x4  = __attribute__((ext_vector_type(4))) float;

static __device__ inline unsigned short f2bf(float x) {
  union { float f; unsigned u; } v; v.f = x;
  unsigned r = v.u + 0x7fff + ((v.u >> 16) & 1);
  return (unsigned short)(r >> 16);
}

// ======== kprep: 4 independent roles fused into one launch, proven shapes ========
//  blk [0,128)      role A: hidden fp32->bf16 + 64-row partial sums   (was kc1b)
//  blk [128,192)    role C: cover + span means                        (was k1a)
//  blk [192,960)    role B: dense_W top -> WtopT bf16 transpose       (was kc2)
//  blk [960,1984)   role D: gauss dims 64..95 of Qa/Ka                (was k4g)
__global__ __launch_bounds__(256) void kprep(
    const float* __restrict__ hidden, const float* __restrict__ dense_W,
    const int* __restrict__ spans, const float* __restrict__ corr,
    const float* __restrict__ gc, const float* __restrict__ gs,
    const float* __restrict__ gw,
    unsigned short* __restrict__ hbf, unsigned short* __restrict__ WtopT,
    float* __restrict__ part, float* __restrict__ nodes, float* __restrict__ cover,
    unsigned short* __restrict__ Qa, unsigned short* __restrict__ Ka) {
  int blk = blockIdx.x, tid = threadIdx.x;
  if (blk < 128) {
    // ---- role A: cvt + partial sums (128 blocks) ----
    int z = blk & 15, b = blk >> 4;
    const float* hb = hidden + (size_t)b * SS * HH;
    unsigned short* ho = hbf + (size_t)b * SS * HH;
    #pragma unroll
    for (int j = 0; j < 3; j++) {
      int c = tid + j * 256;
      float acc = 0.f;
      #pragma unroll 8
      for (int r = z * 64; r < z * 64 + 64; r++) {
        float v = hb[(size_t)r * HH + c];
        ho[(size_t)r * HH + c] = f2bf(v);
        acc += v;
      }
      part[((size_t)b * 16 + z) * HH + c] = acc;
    }
  } else if (blk < 192) {
    // ---- role C: cover + span mean, one block per (span,batch) (64 blocks) ----
    int q = blk - 128;
    int k = q & 7, b = q >> 3;
    __shared__ int sp[KSP * 3];
    if (tid < KSP * 3) sp[tid] = spans[b * KSP * 3 + tid];
    __syncthreads();
    if (tid < 128) {
      int s = k * 128 + tid;
      float c = 0.f;
      #pragma unroll
      for (int kk = 0; kk < KSP; kk++)
        c += (s >= sp[kk * 3] && s <= sp[kk * 3 + 1]) ? 1.f : 0.f;
      cover[b * SS + s] = c;
    }
    int st = sp[k * 3], en = sp[k * 3 + 1];
    float inv = 1.f / (float)(en - st + 1);
    const float* hb = hidden + (size_t)b * SS * HH;
    #pragma unroll
    for (int ci = 0; ci < 3; ci++) {
      int c = tid + ci * 256;
      float a = 0.f;
      #pragma unroll
      for (int j = 0; j < 16; j++) {
        int s = st + j;
        int sc = (s <= en) ? s : en;          // clamp: address always valid
        float v = hb[(size_t)sc * HH + c];    // unconditional load -> pipelines
        a += (s <= en) ? v : 0.f;
      }
      nodes[((size_t)b * NNODES + (k + 1)) * HH + c] = a * inv;
    }
  } else if (blk < 960) {
    // ---- role B: Wtop transpose+cvt (768 blocks) ----
    __shared__ float t[32][33];
    int q = blk - 192;
    int k0 = (q % 24) * 32, n0 = (q / 24) * 32;
    int r = tid >> 3, c4 = (tid & 7) * 4;
    float4 v = *(const float4*)&dense_W[(size_t)(k0 + r) * CDIM + n0 + c4];
    t[r][c4 + 0] = v.x; t[r][c4 + 1] = v.y; t[r][c4 + 2] = v.z; t[r][c4 + 3] = v.w;
    __syncthreads();
    int ro = tid >> 3, co4 = (tid & 7) * 4;
    ushort4 o;
    o.x = f2bf(t[co4 + 0][ro]); o.y = f2bf(t[co4 + 1][ro]);
    o.z = f2bf(t[co4 + 2][ro]); o.w = f2bf(t[co4 + 3][ro]);
    *(ushort4*)&WtopT[(size_t)(n0 + ro) * HH + k0 + co4] = o;
  } else {
    // ---- role D: gauss dims (1024 blocks, k4g shape verbatim) ----
    int g = tid >> 5, lane = tid & 31;
    int row = (blk - 960) * 8 + g;          // global (b,s) row
    int b = row >> 10, s = row & 1023;
    int j = lane & 15;
    int kp = j >> 1, c = j & 1;
    int st = spans[(b * KSP + kp) * 3 + 0];
    int en = spans[(b * KSP + kp) * 3 + 1];
    int et = spans[(b * KSP + kp) * 3 + 2];
    float sig = gs[c], wgt = gw[c], ce = gc[c];
    if (lane < 16) {
      float dx = ((float)(s - st) - ce) / sig;
      float e = wgt * __expf(-0.5f * dx * dx);
      #pragma unroll
      for (int t = 0; t < TT; t++) {
        size_t base = ((size_t)(b * TT + t) * SS + s) * DAUGP;
        Qa[base + 64 + j] = f2bf(corr[et * TT + t] * e);
        Qa[base + 80 + j] = 0;
      }
    } else {
      float dx = ((float)(s - en) - ce) / sig;
      unsigned short bv = f2bf(wgt * __expf(-0.5f * dx * dx));
      #pragma unroll
      for (int t = 0; t < TT; t++) {
        size_t base = ((size_t)(b * TT + t) * SS + s) * DAUGP;
        Ka[base + 64 + j] = bv;
        Ka[base + 80 + j] = 0;
      }
    }
  }
}

// ------ k2: two GAT layers + LN -> enh (1024 threads, 4-way d-split GEMMs) -------
__global__ __launch_bounds__(1024) void k2_gat(
    const float* __restrict__ part, const float* __restrict__ nodes_g,
    const int* __restrict__ spans,
    const float* __restrict__ W1, const float* __restrict__ a_src1,
    const float* __restrict__ a_dst1, const float* __restrict__ b1,
    const float* __restrict__ ln_g, const float* __restrict__ ln_b,
    const float* __restrict__ W2, const float* __restrict__ a_src2,
    const float* __restrict__ a_dst2, const float* __restrict__ b2,
    float* __restrict__ enhg) {
  int b = blockIdx.x, tid = threadIdx.x;
  __shared__ __align__(16) float nod[NNODES * HH];
  __shared__ __align__(16) float hbuf[NNODES * GDIM];
  __shared__ __align__(16) float gbuf[NNODES * GDIM];
  __shared__ __align__(16) float pbuf[4 * NNODES * GDIM];
  __shared__ float asrc[NNODES * NHEADS], adst[NNODES * NHEADS];
  __shared__ float adjm[NNODES * NNODES];
  __shared__ float attn[NNODES * NNODES * NHEADS];
  __shared__ float mu_s[NNODES], rs_s[NNODES];
  __shared__ int sp[KSP * 3];
  if (tid < KSP * 3) sp[tid] = spans[b * KSP * 3 + tid];
  // node 0 = global mean from 16 partials
  for (int c = tid; c < HH; c += 1024) {
    float s = 0.f;
    #pragma unroll
    for (int z = 0; z < 16; z++) s += part[((size_t)b * 16 + z) * HH + c];
    nod[c] = s * (1.f / (float)SS);
  }
  for (int i = tid; i < (NNODES - 1) * HH; i += 1024)
    nod[HH + i] = nodes_g[(size_t)b * NNODES * HH + HH + i];
  __syncthreads();
  { // layer-1 GEMM: quarter q covers d in [q*192, q*192+192)
    int col = tid & 255, q = tid >> 8;
    float acc[NNODES];
    #pragma unroll
    for (int n = 0; n < NNODES; n++) acc[n] = 0.f;
    int dlo = q * 192;
    #pragma unroll 2
    for (int d0 = dlo; d0 < dlo + 192; d0 += 4) {
      float4 nv[NNODES];
      #pragma unroll
      for (int n = 0; n < NNODES; n++) nv[n] = *(const float4*)&nod[n * HH + d0];
      float w0 = W1[(size_t)(d0 + 0) * GDIM + col];
      float w1 = W1[(size_t)(d0 + 1) * GDIM + col];
      float w2 = W1[(size_t)(d0 + 2) * GDIM + col];
      float w3 = W1[(size_t)(d0 + 3) * GDIM + col];
      #pragma unroll
      for (int n = 0; n < NNODES; n++)
        acc[n] += nv[n].x * w0 + nv[n].y * w1 + nv[n].z * w2 + nv[n].w * w3;
    }
    #pragma unroll
    for (int n = 0; n < NNODES; n++) pbuf[(q * NNODES + n) * GDIM + col] = acc[n];
  }
  __syncthreads();
  if (tid < GDIM) {                         // combine quarters
    #pragma unroll
    for (int n = 0; n < NNODES; n++)
      hbuf[n * GDIM + tid] = pbuf[n * GDIM + tid] + pbuf[(NNODES + n) * GDIM + tid]
                           + pbuf[(2 * NNODES + n) * GDIM + tid]
                           + pbuf[(3 * NNODES + n) * GDIM + tid];
  } else if (tid < 256 + NNODES * NNODES) { // adjacency, concurrent thread range
    int q = tid - 256;
    int i = q / NNODES, j = q % NNODES;
    float a = (i == j) ? 1.f : 0.f;
    if (i > 0 && j == 0) a += 1.f;
    if (i == 0 && j > 0) a += 1.f;
    if (i > 0 && j > 0 && i != j) {
      int x = j - 1, y = i - 1;
      int sx = sp[x * 3], ex = sp[x * 3 + 1], sy = sp[y * 3], ey = sp[y * 3 + 1];
      bool same = (sx == sy) && (ex == ey);
      if (sx <= sy && ey <= ex && !same) a += 2.f;
    }
    adjm[q] = a;
  }
  __syncthreads();
  if (tid < NNODES * NHEADS) {
    int n = tid >> 1, hd = tid & 1;
    float sa = 0.f, sd = 0.f;
    #pragma unroll 8
    for (int f = 0; f < HIDD; f++) {
      float v = hbuf[n * GDIM + hd * HIDD + f];
      sa += v * a_src1[hd * HIDD + f];
      sd += v * a_dst1[hd * HIDD + f];
    }
    asrc[tid] = sa; adst[tid] = sd;
  }
  __syncthreads();
  if (tid < NNODES * NHEADS) {
    int d = tid >> 1, hd = tid & 1;
    float sc[NNODES]; float mx = -1e30f;
    for (int s2 = 0; s2 < NNODES; s2++) {
      float a = adjm[d * NNODES + s2]; float v;
      if (a > 0.f) {
        float e = adst[d * 2 + hd] + asrc[s2 * 2 + hd];
        e = (e > 0.f) ? e : 0.2f * e;
        v = e + __logf(a);
      } else v = -1e30f;
      sc[s2] = v; mx = fmaxf(mx, v);
    }
    float ssum = 0.f;
    for (int s2 = 0; s2 < NNODES; s2++) { float ex = __expf(sc[s2] - mx); sc[s2] = ex; ssum += ex; }
    float inv = 1.f / ssum;
    for (int s2 = 0; s2 < NNODES; s2++) attn[(d * NNODES + s2) * NHEADS + hd] = sc[s2] * inv;
  }
  __syncthreads();
  if (tid < 256) {
    int hd = tid >> 7;
    float bbv = b1[tid];
    for (int d = 0; d < NNODES; d++) {
      float acc = bbv;
      #pragma unroll
      for (int s2 = 0; s2 < NNODES; s2++)
        acc += attn[(d * NNODES + s2) * NHEADS + hd] * hbuf[s2 * GDIM + tid];
      gbuf[d * GDIM + tid] = fmaxf(acc, 0.f);
    }
  }
  __syncthreads();
  if (tid < NNODES) {
    float s1 = 0.f, s2v = 0.f;
    #pragma unroll 8
    for (int o = 0; o < GDIM; o++) { float v = gbuf[tid * GDIM + o]; s1 += v; s2v += v * v; }
    float mu = s1 / (float)GDIM;
    float var = s2v / (float)GDIM - mu * mu;
    mu_s[tid] = mu; rs_s[tid] = rsqrtf(var + 1e-5f);
  }
  __syncthreads();
  if (tid < 256) {
    float g = ln_g[tid], bt = ln_b[tid];
    for (int d = 0; d < NNODES; d++)
      gbuf[d * GDIM + tid] = (gbuf[d * GDIM + tid] - mu_s[d]) * rs_s[d] * g + bt;
  }
  __syncthreads();
  { // layer-2 GEMM: quarter q covers d in [q*64, q*64+64)
    int col = tid & 255, q = tid >> 8;
    float acc[NNODES];
    #pragma unroll
    for (int n = 0; n < NNODES; n++) acc[n] = 0.f;
    int dlo = q * 64;
    #pragma unroll 2
    for (int d0 = dlo; d0 < dlo + 64; d0 += 4) {
      float4 nv[NNODES];
      #pragma unroll
      for (int n = 0; n < NNODES; n++) nv[n] = *(const float4*)&gbuf[n * GDIM + d0];
      float w0 = W2[(size_t)(d0 + 0) * GDIM + col];
      float w1 = W2[(size_t)(d0 + 1) * GDIM + col];
      float w2 = W2[(size_t)(d0 + 2) * GDIM + col];
      float w3 = W2[(size_t)(d0 + 3) * GDIM + col];
      #pragma unroll
      for (int n = 0; n < NNODES; n++)
        acc[n] += nv[n].x * w0 + nv[n].y * w1 + nv[n].z * w2 + nv[n].w * w3;
    }
    #pragma unroll
    for (int n = 0; n < NNODES; n++) pbuf[(q * NNODES + n) * GDIM + col] = acc[n];
  }
  __syncthreads();
  if (tid < GDIM) {
    #pragma unroll
    for (int n = 0; n < NNODES; n++)
      hbuf[n * GDIM + tid] = pbuf[n * GDIM + tid] + pbuf[(NNODES + n) * GDIM + tid]
                           + pbuf[(2 * NNODES + n) * GDIM + tid]
                           + pbuf[(3 * NNODES + n) * GDIM + tid];
  }
  __syncthreads();
  if (tid < NNODES * NHEADS) {
    int n = tid >> 1, hd = tid & 1;
    float sa = 0.f, sd = 0.f;
    #pragma unroll 8
    for (int f = 0; f < HIDD; f++) {
      float v = hbuf[n * GDIM + hd * HIDD + f];
      sa += v * a_src2[hd * HIDD + f];
      sd += v * a_dst2[hd * HIDD + f];
    }
    asrc[tid] = sa; adst[tid] = sd;
  }
  __syncthreads();
  if (tid < NNODES * NHEADS) {
    int d = tid >> 1, hd = tid & 1;
    float sc[NNODES]; float mx = -1e30f;
    for (int s2 = 0; s2 < NNODES; s2++) {
      float a = adjm[d * NNODES + s2]; float v;
      if (a > 0.f) {
        float e = adst[d * 2 + hd] + asrc[s2 * 2 + hd];
        e = (e > 0.f) ? e : 0.2f * e;
        v = e + __logf(a);
      } else v = -1e30f;
      sc[s2] = v; mx = fmaxf(mx, v);
    }
    float ssum = 0.f;
    for (int s2 = 0; s2 < NNODES; s2++) { float ex = __expf(sc[s2] - mx); sc[s2] = ex; ssum += ex; }
    float inv = 1.f / ssum;
    for (int s2 = 0; s2 < NNODES; s2++) attn[(d * NNODES + s2) * NHEADS + hd] = sc[s2] * inv;
  }
  __syncthreads();
  if (tid < 256) {
    int hd = tid >> 7;
    float bbv = b2[tid];
    float msum = 0.f;
    for (int d = 0; d < NNODES; d++) {
      float acc = bbv;
      #pragma unroll
      for (int s2 = 0; s2 < NNODES; s2++)
        acc += attn[(d * NNODES + s2) * NHEADS + hd] * hbuf[s2 * GDIM + tid];
      msum += fmaxf(acc, 0.f);
    }
    enhg[b * GDIM + tid] = msum / 9.f;
  }
}

// ---------------- k2b: E2 = enh @ dense_W[768:1024] ------------------------------
__global__ void k2b_e2(const float* __restrict__ enhg, const float* __restrict__ dense_W,
                       float* __restrict__ E2) {
  int b = blockIdx.y, tid = threadIdx.x;
  int o = blockIdx.x * 256 + tid;
  __shared__ __align__(16) float eh[GDIM];
  eh[tid] = enhg[b * GDIM + tid];
  __syncthreads();
  float acc = 0.f;
  #pragma unroll 2
  for (int d = 0; d < GDIM; d += 4) {
    float4 ev = *(const float4*)&eh[d];
    acc += ev.x * dense_W[(size_t)(HH + d + 0) * CDIM + o];
    acc += ev.y * dense_W[(size_t)(HH + d + 1) * CDIM + o];
    acc += ev.z * dense_W[(size_t)(HH + d + 2) * CDIM + o];
    acc += ev.w * dense_W[(size_t)(HH + d + 3) * CDIM + o];
  }
  E2[b * CDIM + o] = acc;
}

// ------- k3: qk = hidden @ Wtop + cover*E2 + b, RoPE fused -> Qa/Ka bf16 ---------
__global__ __launch_bounds__(256) void k3_dense(
    const unsigned short* __restrict__ hbf, const unsigned short* __restrict__ WtopT,
    const float* __restrict__ dense_b, const float* __restrict__ cover,
    const float* __restrict__ E2,
    unsigned short* __restrict__ Qa, unsigned short* __restrict__ Ka) {
  __shared__ unsigned short As[128 * 40];  // [m][kpad=40]
  __shared__ unsigned short Bs[128 * 40];  // [n][kpad=40]
  int tid = threadIdx.x;
  int n0 = blockIdx.x * 128, m0 = blockIdx.y * 128;
  int wave = tid >> 6, lane = tid & 63;
  int wr = wave >> 1, wc = wave & 1;
  int colL = lane & 15, quad = lane >> 4;
  f32x4 acc[4][4];
  #pragma unroll
  for (int i = 0; i < 4; i++)
    #pragma unroll
    for (int j = 0; j < 4; j++) { acc[i][j][0] = 0.f; acc[i][j][1] = 0.f; acc[i][j][2] = 0.f; acc[i][j][3] = 0.f; }
  for (int k0 = 0; k0 < HH; k0 += 32) {
    uint4 va[2], vb[2];
    #pragma unroll
    for (int it = 0; it < 2; it++) {
      int idx = tid + it * 256;           // 0..511
      int r = idx >> 2, seg = idx & 3;
      va[it] = *(const uint4*)(hbf + (size_t)(m0 + r) * HH + k0 + seg * 8);
      vb[it] = *(const uint4*)(WtopT + (size_t)(n0 + r) * HH + k0 + seg * 8);
    }
    __syncthreads();
    #pragma unroll
    for (int it = 0; it < 2; it++) {
      int idx = tid + it * 256;
      int r = idx >> 2, seg = idx & 3;
      *(uint4*)&As[r * 40 + seg * 8] = va[it];
      *(uint4*)&Bs[r * 40 + seg * 8] = vb[it];
    }
    __syncthreads();
    bf16x8 af[4], bf[4];
    #pragma unroll
    for (int tm = 0; tm < 4; tm++)
      af[tm] = *(const bf16x8*)&As[(wr * 64 + tm * 16 + colL) * 40 + quad * 8];
    #pragma unroll
    for (int tn = 0; tn < 4; tn++)
      bf[tn] = *(const bf16x8*)&Bs[(wc * 64 + tn * 16 + colL) * 40 + quad * 8];
    #pragma unroll
    for (int tm = 0; tm < 4; tm++)
      #pragma unroll
      for (int tn = 0; tn < 4; tn++)
        acc[tm][tn] = __builtin_amdgcn_mfma_f32_16x16x32_bf16(af[tm], bf[tn], acc[tm][tn], 0, 0, 0);
  }
  int b = m0 >> 10;
  const float LOG1E4_32 = 0.28782313662425576f;  // ln(10000)/32
  unsigned short* __restrict__ dst = (wc == 0) ? Qa : Ka;
  #pragma unroll
  for (int tn = 0; tn < 4; tn++) {
    int col = n0 + wc * 64 + tn * 16 + colL;
    float e2 = E2[b * CDIM + col];
    float db = dense_b[col];
    int t = col >> 7;
    int dd = tn * 16 + colL;
    int i0 = dd >> 1;
    float inv = __expf(-(float)i0 * LOG1E4_32);
    float sgn = (dd & 1) ? 1.f : -1.f;
    size_t tbase = (size_t)(b * TT + t) * SS;
    #pragma unroll
    for (int tm = 0; tm < 4; tm++) {
      int rbase = m0 + wr * 64 + tm * 16 + quad * 4;
      #pragma unroll
      for (int r = 0; r < 4; r++) {
        int m = rbase + r;
        int s = m & 1023;
        float w = acc[tm][tn][r] + cover[m] * e2 + db;
        float p = __shfl_xor(w, 1, 64);
        float sn, cs;
        __sincosf((float)s * inv, &sn, &cs);
        float o = w * cs + sgn * p * sn;
        dst[(tbase + s) * DAUGP + dd] = f2bf(o);
      }
    }
  }
}

// ---------------- k5: logits = Qa @ Ka^T (MFMA bf16) + mask ----------------------
// Epilogue stages C through LDS (reusing the dead Qs/Ks buffer in two 64-row
// passes) so global stores are float4 / 128B-contiguous instead of 64 scalars.
__global__ __launch_bounds__(256) void k5_logits(
    const unsigned short* __restrict__ Qa, const unsigned short* __restrict__ Ka,
    const float* __restrict__ amask, float* __restrict__ out) {
  int bz = blockIdx.z; int b = bz >> 3;
  int n0 = blockIdx.x * 128, m0 = blockIdx.y * 128;
  int tid = threadIdx.x;
  if (n0 + 127 < m0) {
    // strictly below diagonal: write masked constant
    int r0 = tid >> 5, c4 = (tid & 31) * 4;
    float4 pv = *(const float4*)&amask[b * SS + n0 + c4];
    float4 o;
    o.x = (-(1.f - pv.x) * NEGV - NEGV) * 0.125f;
    o.y = (-(1.f - pv.y) * NEGV - NEGV) * 0.125f;
    o.z = (-(1.f - pv.z) * NEGV - NEGV) * 0.125f;
    o.w = (-(1.f - pv.w) * NEGV - NEGV) * 0.125f;
    for (int r = r0; r < 128; r += 8)
      *(float4*)&out[((size_t)bz * SS + m0 + r) * SS + n0 + c4] = o;
    return;
  }
  __shared__ __align__(16) unsigned short QKs[2 * 128 * 104];  // Qs | Ks, reused as Cs
  unsigned short* Qs = QKs;
  unsigned short* Ks = QKs + 128 * 104;
  const unsigned short* Qrow = Qa + ((size_t)bz * SS + m0) * DAUGP;
  const unsigned short* Krow = Ka + ((size_t)bz * SS + n0) * DAUGP;
  #pragma unroll
  for (int it = 0; it < 6; it++) {
    int idx = tid + it * 256;                // 0..1535
    int r = idx / 12, seg = idx % 12;
    uint4 vq = *(const uint4*)(Qrow + (size_t)r * DAUGP + seg * 8);
    uint4 vk = *(const uint4*)(Krow + (size_t)r * DAUGP + seg * 8);
    *(uint4*)&Qs[r * 104 + seg * 8] = vq;
    *(uint4*)&Ks[r * 104 + seg * 8] = vk;
  }
  __syncthreads();
  int wave = tid >> 6, lane = tid & 63;
  int wr = wave >> 1, wc = wave & 1;
  int colL = lane & 15, quad = lane >> 4;
  f32x4 acc[4][4];
  #pragma unroll
  for (int i = 0; i < 4; i++)
    #pragma unroll
    for (int j = 0; j < 4; j++) { acc[i][j][0] = 0.f; acc[i][j][1] = 0.f; acc[i][j][2] = 0.f; acc[i][j][3] = 0.f; }
  #pragma unroll
  for (int ks = 0; ks < 3; ks++) {
    bf16x8 af[4], bf[4];
    #pragma unroll
    for (int tm = 0; tm < 4; tm++)
      af[tm] = *(const bf16x8*)&Qs[(wr * 64 + tm * 16 + colL) * 104 + ks * 32 + quad * 8];
    #pragma unroll
    for (int tn = 0; tn < 4; tn++)
      bf[tn] = *(const bf16x8*)&Ks[(wc * 64 + tn * 16 + colL) * 104 + ks * 32 + quad * 8];
    #pragma unroll
    for (int tm = 0; tm < 4; tm++)
      #pragma unroll
      for (int tn = 0; tn < 4; tn++)
        acc[tm][tn] = __builtin_amdgcn_mfma_f32_16x16x32_bf16(af[tm], bf[tn], acc[tm][tn], 0, 0, 0);
  }
  // ---- staged epilogue: two 64-row passes through LDS, float4 stores ----
  float* Cs = (float*)QKs;                   // 64*132*4 = 33.8KB <= 53.2KB
  #pragma unroll
  for (int h = 0; h < 2; h++) {
    __syncthreads();                         // Qs/Ks (or prev Cs pass) dead
    if (wr == h) {
      #pragma unroll
      for (int tn = 0; tn < 4; tn++) {
        int cloc = wc * 64 + tn * 16 + colL; // 0..127 within tile
        float p = amask[b * SS + n0 + cloc];
        float negp = -(1.f - p) * NEGV;
        #pragma unroll
        for (int tm = 0; tm < 4; tm++) {
          int rloc = tm * 16 + quad * 4;     // 0..63 within this half
          #pragma unroll
          for (int r = 0; r < 4; r++) {
            int m = m0 + h * 64 + rloc + r;
            float v = acc[tm][tn][r] * p + negp;
            if (n0 + cloc < m) v -= NEGV;
            Cs[(rloc + r) * 132 + cloc] = v * 0.125f;
          }
        }
      }
    }
    __syncthreads();
    int row = tid >> 2, seg = tid & 3;       // 64 rows x 4 segments of 32 floats
    const float* src = &Cs[row * 132 + seg * 32];
    float* dstp = &out[((size_t)bz * SS + m0 + h * 64 + row) * SS + n0 + seg * 32];
    #pragma unroll
    for (int j = 0; j < 8; j++)
      *(float4*)(dstp + j * 4) = *(const float4*)(src + j * 4);
  }
}

extern "C" void kernel_launch(void* const* d_in, const int* in_sizes, int n_in,
                              void* d_out, int out_size, void* d_ws, size_t ws_size,
                              hipStream_t stream) {
  const float* hidden  = (const float*)d_in[0];
  const float* amask   = (const float*)d_in[1];
  const int*   spans   = (const int*)d_in[2];
  const float* W1      = (const float*)d_in[3];
  const float* a_src1  = (const float*)d_in[4];
  const float* a_dst1  = (const float*)d_in[5];
  const float* b1      = (const float*)d_in[6];
  const float* ln_g    = (const float*)d_in[7];
  const float* ln_b    = (const float*)d_in[8];
  const float* W2      = (const float*)d_in[9];
  const float* a_src2  = (const float*)d_in[10];
  const float* a_dst2  = (const float*)d_in[11];
  const float* b2      = (const float*)d_in[12];
  const float* dense_W = (const float*)d_in[13];
  const float* dense_b = (const float*)d_in[14];
  const float* gc      = (const float*)d_in[15];
  const float* gs      = (const float*)d_in[16];
  const float* gw      = (const float*)d_in[17];
  const float* corr    = (const float*)d_in[18];

  char* wsb = (char*)d_ws;
  unsigned short* hbf  = (unsigned short*)wsb;                wsb += (size_t)BB * SS * HH * 2;          // 12.6 MB
  unsigned short* WtopT= (unsigned short*)wsb;                wsb += (size_t)CDIM * HH * 2;             // 1.57 MB
  unsigned short* Qa   = (unsigned short*)wsb;                wsb += (size_t)BB * TT * SS * DAUGP * 2;  // 12.6 MB
  unsigned short* Ka   = (unsigned short*)wsb;                wsb += (size_t)BB * TT * SS * DAUGP * 2;  // 12.6 MB
  float* nodes         = (float*)wsb;                         wsb += (size_t)BB * NNODES * HH * 4;
  float* cover         = (float*)wsb;                         wsb += (size_t)BB * SS * 4;
  float* E2            = (float*)wsb;                         wsb += (size_t)BB * CDIM * 4;
  float* enhg          = (float*)wsb;                         wsb += (size_t)BB * GDIM * 4;
  float* part          = (float*)wsb;                         wsb += (size_t)BB * 16 * HH * 4;
  float* outp = (float*)d_out;

  kprep<<<1984, 256, 0, stream>>>(hidden, dense_W, spans, corr, gc, gs, gw,
                                  hbf, WtopT, part, nodes, cover, Qa, Ka);
  k2_gat<<<BB, 1024, 0, stream>>>(part, nodes, spans, W1, a_src1, a_dst1, b1, ln_g, ln_b,
                                  W2, a_src2, a_dst2, b2, enhg);
  k2b_e2<<<dim3(CDIM / 256, BB), 256, 0, stream>>>(enhg, dense_W, E2);
  k3_dense<<<dim3(CDIM / 128, (BB * SS) / 128), 256, 0, stream>>>(hbf, WtopT, dense_b,
                                                                  cover, E2, Qa, Ka);
  k5_logits<<<dim3(8, 8, BB * TT), 256, 0, stream>>>(Qa, Ka, amask, outp);
}

// Round 6
// 511.010 us; speedup vs baseline: 1.0886x; 1.0886x over previous
//
#include <hip/hip_runtime.h>
#include <cstdint>
#include <cstddef>

#define BB 8
#define SS 1024
#define HH 768
#define TT 8
#define DII 64
#define HIDD 128
#define KSP 8
#define NHEADS 2
#define NNODES 9
#define GDIM 256   // NHEADS*HIDD
#define CDIM 1024  // TT*2*DII == HH+GDIM
#define DAUGP 96   // 64 rope + 16 gauss + 16 zero pad (3 x 32-k MFMA slabs)
#define NEGV 1e12f

using bf16x8 = __attribute__((ext_vector_type(8))) __bf16;
using f32x4  = __attribute__((ext_vector_type(4))) float;

static __device__ inline unsigned short f2bf(float x) {
  union { float f; unsigned u; } v; v.f = x;
  unsigned r = v.u + 0x7fff + ((v.u >> 16) & 1);
  return (unsigned short)(r >> 16);
}

// ======== kprep: 4 independent roles fused into one launch, proven shapes ========
//  blk [0,128)      role A: hidden fp32->bf16 + 64-row partial sums   (was kc1b)
//  blk [128,192)    role C: cover + span means                        (was k1a)
//  blk [192,960)    role B: dense_W top -> WtopT bf16 transpose       (was kc2)
//  blk [960,1984)   role D: gauss dims 64..95 of Qa/Ka                (was k4g)
__global__ __launch_bounds__(256) void kprep(
    const float* __restrict__ hidden, const float* __restrict__ dense_W,
    const int* __restrict__ spans, const float* __restrict__ corr,
    const float* __restrict__ gc, const float* __restrict__ gs,
    const float* __restrict__ gw,
    unsigned short* __restrict__ hbf, unsigned short* __restrict__ WtopT,
    float* __restrict__ part, float* __restrict__ nodes, float* __restrict__ cover,
    unsigned short* __restrict__ Qa, unsigned short* __restrict__ Ka) {
  int blk = blockIdx.x, tid = threadIdx.x;
  if (blk < 128) {
    // ---- role A: cvt + partial sums (128 blocks) ----
    int z = blk & 15, b = blk >> 4;
    const float* hb = hidden + (size_t)b * SS * HH;
    unsigned short* ho = hbf + (size_t)b * SS * HH;
    #pragma unroll
    for (int j = 0; j < 3; j++) {
      int c = tid + j * 256;
      float acc = 0.f;
      #pragma unroll 8
      for (int r = z * 64; r < z * 64 + 64; r++) {
        float v = hb[(size_t)r * HH + c];
        ho[(size_t)r * HH + c] = f2bf(v);
        acc += v;
      }
      part[((size_t)b * 16 + z) * HH + c] = acc;
    }
  } else if (blk < 192) {
    // ---- role C: cover + span mean, one block per (span,batch) (64 blocks) ----
    int q = blk - 128;
    int k = q & 7, b = q >> 3;
    __shared__ int sp[KSP * 3];
    if (tid < KSP * 3) sp[tid] = spans[b * KSP * 3 + tid];
    __syncthreads();
    if (tid < 128) {
      int s = k * 128 + tid;
      float c = 0.f;
      #pragma unroll
      for (int kk = 0; kk < KSP; kk++)
        c += (s >= sp[kk * 3] && s <= sp[kk * 3 + 1]) ? 1.f : 0.f;
      cover[b * SS + s] = c;
    }
    int st = sp[k * 3], en = sp[k * 3 + 1];
    float inv = 1.f / (float)(en - st + 1);
    const float* hb = hidden + (size_t)b * SS * HH;
    #pragma unroll
    for (int ci = 0; ci < 3; ci++) {
      int c = tid + ci * 256;
      float a = 0.f;
      #pragma unroll
      for (int j = 0; j < 16; j++) {
        int s = st + j;
        int sc = (s <= en) ? s : en;          // clamp: address always valid
        float v = hb[(size_t)sc * HH + c];    // unconditional load -> pipelines
        a += (s <= en) ? v : 0.f;
      }
      nodes[((size_t)b * NNODES + (k + 1)) * HH + c] = a * inv;
    }
  } else if (blk < 960) {
    // ---- role B: Wtop transpose+cvt (768 blocks) ----
    __shared__ float t[32][33];
    int q = blk - 192;
    int k0 = (q % 24) * 32, n0 = (q / 24) * 32;
    int r = tid >> 3, c4 = (tid & 7) * 4;
    float4 v = *(const float4*)&dense_W[(size_t)(k0 + r) * CDIM + n0 + c4];
    t[r][c4 + 0] = v.x; t[r][c4 + 1] = v.y; t[r][c4 + 2] = v.z; t[r][c4 + 3] = v.w;
    __syncthreads();
    int ro = tid >> 3, co4 = (tid & 7) * 4;
    ushort4 o;
    o.x = f2bf(t[co4 + 0][ro]); o.y = f2bf(t[co4 + 1][ro]);
    o.z = f2bf(t[co4 + 2][ro]); o.w = f2bf(t[co4 + 3][ro]);
    *(ushort4*)&WtopT[(size_t)(n0 + ro) * HH + k0 + co4] = o;
  } else {
    // ---- role D: gauss dims (1024 blocks, k4g shape verbatim) ----
    int g = tid >> 5, lane = tid & 31;
    int row = (blk - 960) * 8 + g;          // global (b,s) row
    int b = row >> 10, s = row & 1023;
    int j = lane & 15;
    int kp = j >> 1, c = j & 1;
    int st = spans[(b * KSP + kp) * 3 + 0];
    int en = spans[(b * KSP + kp) * 3 + 1];
    int et = spans[(b * KSP + kp) * 3 + 2];
    float sig = gs[c], wgt = gw[c], ce = gc[c];
    if (lane < 16) {
      float dx = ((float)(s - st) - ce) / sig;
      float e = wgt * __expf(-0.5f * dx * dx);
      #pragma unroll
      for (int t = 0; t < TT; t++) {
        size_t base = ((size_t)(b * TT + t) * SS + s) * DAUGP;
        Qa[base + 64 + j] = f2bf(corr[et * TT + t] * e);
        Qa[base + 80 + j] = 0;
      }
    } else {
      float dx = ((float)(s - en) - ce) / sig;
      unsigned short bv = f2bf(wgt * __expf(-0.5f * dx * dx));
      #pragma unroll
      for (int t = 0; t < TT; t++) {
        size_t base = ((size_t)(b * TT + t) * SS + s) * DAUGP;
        Ka[base + 64 + j] = bv;
        Ka[base + 80 + j] = 0;
      }
    }
  }
}

// ------ k2: two GAT layers + LN -> enh (1024 threads, 4-way d-split GEMMs) -------
__global__ __launch_bounds__(1024) void k2_gat(
    const float* __restrict__ part, const float* __restrict__ nodes_g,
    const int* __restrict__ spans,
    const float* __restrict__ W1, const float* __restrict__ a_src1,
    const float* __restrict__ a_dst1, const float* __restrict__ b1,
    const float* __restrict__ ln_g, const float* __restrict__ ln_b,
    const float* __restrict__ W2, const float* __restrict__ a_src2,
    const float* __restrict__ a_dst2, const float* __restrict__ b2,
    float* __restrict__ enhg) {
  int b = blockIdx.x, tid = threadIdx.x;
  __shared__ __align__(16) float nod[NNODES * HH];
  __shared__ __align__(16) float hbuf[NNODES * GDIM];
  __shared__ __align__(16) float gbuf[NNODES * GDIM];
  __shared__ __align__(16) float pbuf[4 * NNODES * GDIM];
  __shared__ float asrc[NNODES * NHEADS], adst[NNODES * NHEADS];
  __shared__ float adjm[NNODES * NNODES];
  __shared__ float attn[NNODES * NNODES * NHEADS];
  __shared__ float mu_s[NNODES], rs_s[NNODES];
  __shared__ int sp[KSP * 3];
  if (tid < KSP * 3) sp[tid] = spans[b * KSP * 3 + tid];
  // node 0 = global mean from 16 partials
  for (int c = tid; c < HH; c += 1024) {
    float s = 0.f;
    #pragma unroll
    for (int z = 0; z < 16; z++) s += part[((size_t)b * 16 + z) * HH + c];
    nod[c] = s * (1.f / (float)SS);
  }
  for (int i = tid; i < (NNODES - 1) * HH; i += 1024)
    nod[HH + i] = nodes_g[(size_t)b * NNODES * HH + HH + i];
  __syncthreads();
  { // layer-1 GEMM: quarter q covers d in [q*192, q*192+192)
    int col = tid & 255, q = tid >> 8;
    float acc[NNODES];
    #pragma unroll
    for (int n = 0; n < NNODES; n++) acc[n] = 0.f;
    int dlo = q * 192;
    #pragma unroll 2
    for (int d0 = dlo; d0 < dlo + 192; d0 += 4) {
      float4 nv[NNODES];
      #pragma unroll
      for (int n = 0; n < NNODES; n++) nv[n] = *(const float4*)&nod[n * HH + d0];
      float w0 = W1[(size_t)(d0 + 0) * GDIM + col];
      float w1 = W1[(size_t)(d0 + 1) * GDIM + col];
      float w2 = W1[(size_t)(d0 + 2) * GDIM + col];
      float w3 = W1[(size_t)(d0 + 3) * GDIM + col];
      #pragma unroll
      for (int n = 0; n < NNODES; n++)
        acc[n] += nv[n].x * w0 + nv[n].y * w1 + nv[n].z * w2 + nv[n].w * w3;
    }
    #pragma unroll
    for (int n = 0; n < NNODES; n++) pbuf[(q * NNODES + n) * GDIM + col] = acc[n];
  }
  __syncthreads();
  if (tid < GDIM) {                         // combine quarters
    #pragma unroll
    for (int n = 0; n < NNODES; n++)
      hbuf[n * GDIM + tid] = pbuf[n * GDIM + tid] + pbuf[(NNODES + n) * GDIM + tid]
                           + pbuf[(2 * NNODES + n) * GDIM + tid]
                           + pbuf[(3 * NNODES + n) * GDIM + tid];
  } else if (tid < 256 + NNODES * NNODES) { // adjacency, concurrent thread range
    int q = tid - 256;
    int i = q / NNODES, j = q % NNODES;
    float a = (i == j) ? 1.f : 0.f;
    if (i > 0 && j == 0) a += 1.f;
    if (i == 0 && j > 0) a += 1.f;
    if (i > 0 && j > 0 && i != j) {
      int x = j - 1, y = i - 1;
      int sx = sp[x * 3], ex = sp[x * 3 + 1], sy = sp[y * 3], ey = sp[y * 3 + 1];
      bool same = (sx == sy) && (ex == ey);
      if (sx <= sy && ey <= ex && !same) a += 2.f;
    }
    adjm[q] = a;
  }
  __syncthreads();
  if (tid < NNODES * NHEADS) {
    int n = tid >> 1, hd = tid & 1;
    float sa = 0.f, sd = 0.f;
    #pragma unroll 8
    for (int f = 0; f < HIDD; f++) {
      float v = hbuf[n * GDIM + hd * HIDD + f];
      sa += v * a_src1[hd * HIDD + f];
      sd += v * a_dst1[hd * HIDD + f];
    }
    asrc[tid] = sa; adst[tid] = sd;
  }
  __syncthreads();
  if (tid < NNODES * NHEADS) {
    int d = tid >> 1, hd = tid & 1;
    float sc[NNODES]; float mx = -1e30f;
    for (int s2 = 0; s2 < NNODES; s2++) {
      float a = adjm[d * NNODES + s2]; float v;
      if (a > 0.f) {
        float e = adst[d * 2 + hd] + asrc[s2 * 2 + hd];
        e = (e > 0.f) ? e : 0.2f * e;
        v = e + __logf(a);
      } else v = -1e30f;
      sc[s2] = v; mx = fmaxf(mx, v);
    }
    float ssum = 0.f;
    for (int s2 = 0; s2 < NNODES; s2++) { float ex = __expf(sc[s2] - mx); sc[s2] = ex; ssum += ex; }
    float inv = 1.f / ssum;
    for (int s2 = 0; s2 < NNODES; s2++) attn[(d * NNODES + s2) * NHEADS + hd] = sc[s2] * inv;
  }
  __syncthreads();
  if (tid < 256) {
    int hd = tid >> 7;
    float bbv = b1[tid];
    for (int d = 0; d < NNODES; d++) {
      float acc = bbv;
      #pragma unroll
      for (int s2 = 0; s2 < NNODES; s2++)
        acc += attn[(d * NNODES + s2) * NHEADS + hd] * hbuf[s2 * GDIM + tid];
      gbuf[d * GDIM + tid] = fmaxf(acc, 0.f);
    }
  }
  __syncthreads();
  if (tid < NNODES) {
    float s1 = 0.f, s2v = 0.f;
    #pragma unroll 8
    for (int o = 0; o < GDIM; o++) { float v = gbuf[tid * GDIM + o]; s1 += v; s2v += v * v; }
    float mu = s1 / (float)GDIM;
    float var = s2v / (float)GDIM - mu * mu;
    mu_s[tid] = mu; rs_s[tid] = rsqrtf(var + 1e-5f);
  }
  __syncthreads();
  if (tid < 256) {
    float g = ln_g[tid], bt = ln_b[tid];
    for (int d = 0; d < NNODES; d++)
      gbuf[d * GDIM + tid] = (gbuf[d * GDIM + tid] - mu_s[d]) * rs_s[d] * g + bt;
  }
  __syncthreads();
  { // layer-2 GEMM: quarter q covers d in [q*64, q*64+64)
    int col = tid & 255, q = tid >> 8;
    float acc[NNODES];
    #pragma unroll
    for (int n = 0; n < NNODES; n++) acc[n] = 0.f;
    int dlo = q * 64;
    #pragma unroll 2
    for (int d0 = dlo; d0 < dlo + 64; d0 += 4) {
      float4 nv[NNODES];
      #pragma unroll
      for (int n = 0; n < NNODES; n++) nv[n] = *(const float4*)&gbuf[n * GDIM + d0];
      float w0 = W2[(size_t)(d0 + 0) * GDIM + col];
      float w1 = W2[(size_t)(d0 + 1) * GDIM + col];
      float w2 = W2[(size_t)(d0 + 2) * GDIM + col];
      float w3 = W2[(size_t)(d0 + 3) * GDIM + col];
      #pragma unroll
      for (int n = 0; n < NNODES; n++)
        acc[n] += nv[n].x * w0 + nv[n].y * w1 + nv[n].z * w2 + nv[n].w * w3;
    }
    #pragma unroll
    for (int n = 0; n < NNODES; n++) pbuf[(q * NNODES + n) * GDIM + col] = acc[n];
  }
  __syncthreads();
  if (tid < GDIM) {
    #pragma unroll
    for (int n = 0; n < NNODES; n++)
      hbuf[n * GDIM + tid] = pbuf[n * GDIM + tid] + pbuf[(NNODES + n) * GDIM + tid]
                           + pbuf[(2 * NNODES + n) * GDIM + tid]
                           + pbuf[(3 * NNODES + n) * GDIM + tid];
  }
  __syncthreads();
  if (tid < NNODES * NHEADS) {
    int n = tid >> 1, hd = tid & 1;
    float sa = 0.f, sd = 0.f;
    #pragma unroll 8
    for (int f = 0; f < HIDD; f++) {
      float v = hbuf[n * GDIM + hd * HIDD + f];
      sa += v * a_src2[hd * HIDD + f];
      sd += v * a_dst2[hd * HIDD + f];
    }
    asrc[tid] = sa; adst[tid] = sd;
  }
  __syncthreads();
  if (tid < NNODES * NHEADS) {
    int d = tid >> 1, hd = tid & 1;
    float sc[NNODES]; float mx = -1e30f;
    for (int s2 = 0; s2 < NNODES; s2++) {
      float a = adjm[d * NNODES + s2]; float v;
      if (a > 0.f) {
        float e = adst[d * 2 + hd] + asrc[s2 * 2 + hd];
        e = (e > 0.f) ? e : 0.2f * e;
        v = e + __logf(a);
      } else v = -1e30f;
      sc[s2] = v; mx = fmaxf(mx, v);
    }
    float ssum = 0.f;
    for (int s2 = 0; s2 < NNODES; s2++) { float ex = __expf(sc[s2] - mx); sc[s2] = ex; ssum += ex; }
    float inv = 1.f / ssum;
    for (int s2 = 0; s2 < NNODES; s2++) attn[(d * NNODES + s2) * NHEADS + hd] = sc[s2] * inv;
  }
  __syncthreads();
  if (tid < 256) {
    int hd = tid >> 7;
    float bbv = b2[tid];
    float msum = 0.f;
    for (int d = 0; d < NNODES; d++) {
      float acc = bbv;
      #pragma unroll
      for (int s2 = 0; s2 < NNODES; s2++)
        acc += attn[(d * NNODES + s2) * NHEADS + hd] * hbuf[s2 * GDIM + tid];
      msum += fmaxf(acc, 0.f);
    }
    enhg[b * GDIM + tid] = msum / 9.f;
  }
}

// ---------------- k2b: E2 = enh @ dense_W[768:1024] ------------------------------
__global__ void k2b_e2(const float* __restrict__ enhg, const float* __restrict__ dense_W,
                       float* __restrict__ E2) {
  int b = blockIdx.y, tid = threadIdx.x;
  int o = blockIdx.x * 256 + tid;
  __shared__ __align__(16) float eh[GDIM];
  eh[tid] = enhg[b * GDIM + tid];
  __syncthreads();
  float acc = 0.f;
  #pragma unroll 2
  for (int d = 0; d < GDIM; d += 4) {
    float4 ev = *(const float4*)&eh[d];
    acc += ev.x * dense_W[(size_t)(HH + d + 0) * CDIM + o];
    acc += ev.y * dense_W[(size_t)(HH + d + 1) * CDIM + o];
    acc += ev.z * dense_W[(size_t)(HH + d + 2) * CDIM + o];
    acc += ev.w * dense_W[(size_t)(HH + d + 3) * CDIM + o];
  }
  E2[b * CDIM + o] = acc;
}

// ------- k3: qk = hidden @ Wtop + cover*E2 + b, RoPE fused -> Qa/Ka bf16 ---------
// Staging now via global_load_lds width=16 into LINEAR [128][32] LDS (m97
// structure): wave-uniform LDS base + lane*16B; per-lane global src matches
// (row = chunk*16 + lane/4, 16B seg = lane&3). No reg round-trip, no ds_write.
__global__ __launch_bounds__(256) void k3_dense(
    const unsigned short* __restrict__ hbf, const unsigned short* __restrict__ WtopT,
    const float* __restrict__ dense_b, const float* __restrict__ cover,
    const float* __restrict__ E2,
    unsigned short* __restrict__ Qa, unsigned short* __restrict__ Ka) {
  __shared__ __align__(16) unsigned short As[128 * 32];  // linear, 8KB
  __shared__ __align__(16) unsigned short Bs[128 * 32];  // linear, 8KB
  int tid = threadIdx.x;
  int n0 = blockIdx.x * 128, m0 = blockIdx.y * 128;
  int wave = tid >> 6, lane = tid & 63;
  int wr = wave >> 1, wc = wave & 1;
  int colL = lane & 15, quad = lane >> 4;
  int srow = lane >> 2;            // row within 16-row chunk
  int sseg = lane & 3;             // 16B segment within 64B row
  f32x4 acc[4][4];
  #pragma unroll
  for (int i = 0; i < 4; i++)
    #pragma unroll
    for (int j = 0; j < 4; j++) { acc[i][j][0] = 0.f; acc[i][j][1] = 0.f; acc[i][j][2] = 0.f; acc[i][j][3] = 0.f; }
  for (int k0 = 0; k0 < HH; k0 += 32) {
    #pragma unroll
    for (int j = 0; j < 2; j++) {
      int chunk = wave * 2 + j;                  // 0..7: rows [chunk*16, +16)
      int row = chunk * 16 + srow;
      const unsigned short* ga = hbf   + (size_t)(m0 + row) * HH + k0 + sseg * 8;
      const unsigned short* gb = WtopT + (size_t)(n0 + row) * HH + k0 + sseg * 8;
      __builtin_amdgcn_global_load_lds(
          (const __attribute__((address_space(1))) unsigned int*)ga,
          (__attribute__((address_space(3))) unsigned int*)(As + chunk * 512), 16, 0, 0);
      __builtin_amdgcn_global_load_lds(
          (const __attribute__((address_space(1))) unsigned int*)gb,
          (__attribute__((address_space(3))) unsigned int*)(Bs + chunk * 512), 16, 0, 0);
    }
    __syncthreads();                             // drains vmcnt -> LDS ready
    bf16x8 af[4], bf[4];
    #pragma unroll
    for (int tm = 0; tm < 4; tm++)
      af[tm] = *(const bf16x8*)&As[(wr * 64 + tm * 16 + colL) * 32 + quad * 8];
    #pragma unroll
    for (int tn = 0; tn < 4; tn++)
      bf[tn] = *(const bf16x8*)&Bs[(wc * 64 + tn * 16 + colL) * 32 + quad * 8];
    #pragma unroll
    for (int tm = 0; tm < 4; tm++)
      #pragma unroll
      for (int tn = 0; tn < 4; tn++)
        acc[tm][tn] = __builtin_amdgcn_mfma_f32_16x16x32_bf16(af[tm], bf[tn], acc[tm][tn], 0, 0, 0);
    __syncthreads();                             // frags read; LDS reusable
  }
  int b = m0 >> 10;
  const float LOG1E4_32 = 0.28782313662425576f;  // ln(10000)/32
  unsigned short* __restrict__ dst = (wc == 0) ? Qa : Ka;
  #pragma unroll
  for (int tn = 0; tn < 4; tn++) {
    int col = n0 + wc * 64 + tn * 16 + colL;
    float e2 = E2[b * CDIM + col];
    float db = dense_b[col];
    int t = col >> 7;
    int dd = tn * 16 + colL;
    int i0 = dd >> 1;
    float inv = __expf(-(float)i0 * LOG1E4_32);
    float sgn = (dd & 1) ? 1.f : -1.f;
    size_t tbase = (size_t)(b * TT + t) * SS;
    #pragma unroll
    for (int tm = 0; tm < 4; tm++) {
      int rbase = m0 + wr * 64 + tm * 16 + quad * 4;
      #pragma unroll
      for (int r = 0; r < 4; r++) {
        int m = rbase + r;
        int s = m & 1023;
        float w = acc[tm][tn][r] + cover[m] * e2 + db;
        float p = __shfl_xor(w, 1, 64);
        float sn, cs;
        __sincosf((float)s * inv, &sn, &cs);
        float o = w * cs + sgn * p * sn;
        dst[(tbase + s) * DAUGP + dd] = f2bf(o);
      }
    }
  }
}

// ---------------- k5: logits = Qa @ Ka^T (MFMA bf16) + mask ----------------------
// Epilogue stages C through LDS (reusing the dead Qs/Ks buffer in two 64-row
// passes) so global stores are float4 / 128B-contiguous instead of 64 scalars.
__global__ __launch_bounds__(256) void k5_logits(
    const unsigned short* __restrict__ Qa, const unsigned short* __restrict__ Ka,
    const float* __restrict__ amask, float* __restrict__ out) {
  int bz = blockIdx.z; int b = bz >> 3;
  int n0 = blockIdx.x * 128, m0 = blockIdx.y * 128;
  int tid = threadIdx.x;
  if (n0 + 127 < m0) {
    // strictly below diagonal: write masked constant
    int r0 = tid >> 5, c4 = (tid & 31) * 4;
    float4 pv = *(const float4*)&amask[b * SS + n0 + c4];
    float4 o;
    o.x = (-(1.f - pv.x) * NEGV - NEGV) * 0.125f;
    o.y = (-(1.f - pv.y) * NEGV - NEGV) * 0.125f;
    o.z = (-(1.f - pv.z) * NEGV - NEGV) * 0.125f;
    o.w = (-(1.f - pv.w) * NEGV - NEGV) * 0.125f;
    for (int r = r0; r < 128; r += 8)
      *(float4*)&out[((size_t)bz * SS + m0 + r) * SS + n0 + c4] = o;
    return;
  }
  __shared__ __align__(16) unsigned short QKs[2 * 128 * 104];  // Qs | Ks, reused as Cs
  unsigned short* Qs = QKs;
  unsigned short* Ks = QKs + 128 * 104;
  const unsigned short* Qrow = Qa + ((size_t)bz * SS + m0) * DAUGP;
  const unsigned short* Krow = Ka + ((size_t)bz * SS + n0) * DAUGP;
  #pragma unroll
  for (int it = 0; it < 6; it++) {
    int idx = tid + it * 256;                // 0..1535
    int r = idx / 12, seg = idx % 12;
    uint4 vq = *(const uint4*)(Qrow + (size_t)r * DAUGP + seg * 8);
    uint4 vk = *(const uint4*)(Krow + (size_t)r * DAUGP + seg * 8);
    *(uint4*)&Qs[r * 104 + seg * 8] = vq;
    *(uint4*)&Ks[r * 104 + seg * 8] = vk;
  }
  __syncthreads();
  int wave = tid >> 6, lane = tid & 63;
  int wr = wave >> 1, wc = wave & 1;
  int colL = lane & 15, quad = lane >> 4;
  f32x4 acc[4][4];
  #pragma unroll
  for (int i = 0; i < 4; i++)
    #pragma unroll
    for (int j = 0; j < 4; j++) { acc[i][j][0] = 0.f; acc[i][j][1] = 0.f; acc[i][j][2] = 0.f; acc[i][j][3] = 0.f; }
  #pragma unroll
  for (int ks = 0; ks < 3; ks++) {
    bf16x8 af[4], bf[4];
    #pragma unroll
    for (int tm = 0; tm < 4; tm++)
      af[tm] = *(const bf16x8*)&Qs[(wr * 64 + tm * 16 + colL) * 104 + ks * 32 + quad * 8];
    #pragma unroll
    for (int tn = 0; tn < 4; tn++)
      bf[tn] = *(const bf16x8*)&Ks[(wc * 64 + tn * 16 + colL) * 104 + ks * 32 + quad * 8];
    #pragma unroll
    for (int tm = 0; tm < 4; tm++)
      #pragma unroll
      for (int tn = 0; tn < 4; tn++)
        acc[tm][tn] = __builtin_amdgcn_mfma_f32_16x16x32_bf16(af[tm], bf[tn], acc[tm][tn], 0, 0, 0);
  }
  // ---- staged epilogue: two 64-row passes through LDS, float4 stores ----
  float* Cs = (float*)QKs;                   // 64*132*4 = 33.8KB <= 53.2KB
  #pragma unroll
  for (int h = 0; h < 2; h++) {
    __syncthreads();                         // Qs/Ks (or prev Cs pass) dead
    if (wr == h) {
      #pragma unroll
      for (int tn = 0; tn < 4; tn++) {
        int cloc = wc * 64 + tn * 16 + colL; // 0..127 within tile
        float p = amask[b * SS + n0 + cloc];
        float negp = -(1.f - p) * NEGV;
        #pragma unroll
        for (int tm = 0; tm < 4; tm++) {
          int rloc = tm * 16 + quad * 4;     // 0..63 within this half
          #pragma unroll
          for (int r = 0; r < 4; r++) {
            int m = m0 + h * 64 + rloc + r;
            float v = acc[tm][tn][r] * p + negp;
            if (n0 + cloc < m) v -= NEGV;
            Cs[(rloc + r) * 132 + cloc] = v * 0.125f;
          }
        }
      }
    }
    __syncthreads();
    int row = tid >> 2, seg = tid & 3;       // 64 rows x 4 segments of 32 floats
    const float* src = &Cs[row * 132 + seg * 32];
    float* dstp = &out[((size_t)bz * SS + m0 + h * 64 + row) * SS + n0 + seg * 32];
    #pragma unroll
    for (int j = 0; j < 8; j++)
      *(float4*)(dstp + j * 4) = *(const float4*)(src + j * 4);
  }
}

extern "C" void kernel_launch(void* const* d_in, const int* in_sizes, int n_in,
                              void* d_out, int out_size, void* d_ws, size_t ws_size,
                              hipStream_t stream) {
  const float* hidden  = (const float*)d_in[0];
  const float* amask   = (const float*)d_in[1];
  const int*   spans   = (const int*)d_in[2];
  const float* W1      = (const float*)d_in[3];
  const float* a_src1  = (const float*)d_in[4];
  const float* a_dst1  = (const float*)d_in[5];
  const float* b1      = (const float*)d_in[6];
  const float* ln_g    = (const float*)d_in[7];
  const float* ln_b    = (const float*)d_in[8];
  const float* W2      = (const float*)d_in[9];
  const float* a_src2  = (const float*)d_in[10];
  const float* a_dst2  = (const float*)d_in[11];
  const float* b2      = (const float*)d_in[12];
  const float* dense_W = (const float*)d_in[13];
  const float* dense_b = (const float*)d_in[14];
  const float* gc      = (const float*)d_in[15];
  const float* gs      = (const float*)d_in[16];
  const float* gw      = (const float*)d_in[17];
  const float* corr    = (const float*)d_in[18];

  char* wsb = (char*)d_ws;
  unsigned short* hbf  = (unsigned short*)wsb;                wsb += (size_t)BB * SS * HH * 2;          // 12.6 MB
  unsigned short* WtopT= (unsigned short*)wsb;                wsb += (size_t)CDIM * HH * 2;             // 1.57 MB
  unsigned short* Qa   = (unsigned short*)wsb;                wsb += (size_t)BB * TT * SS * DAUGP * 2;  // 12.6 MB
  unsigned short* Ka   = (unsigned short*)wsb;                wsb += (size_t)BB * TT * SS * DAUGP * 2;  // 12.6 MB
  float* nodes         = (float*)wsb;                         wsb += (size_t)BB * NNODES * HH * 4;
  float* cover         = (float*)wsb;                         wsb += (size_t)BB * SS * 4;
  float* E2            = (float*)wsb;                         wsb += (size_t)BB * CDIM * 4;
  float* enhg          = (float*)wsb;                         wsb += (size_t)BB * GDIM * 4;
  float* part          = (float*)wsb;                         wsb += (size_t)BB * 16 * HH * 4;
  float* outp = (float*)d_out;

  kprep<<<1984, 256, 0, stream>>>(hidden, dense_W, spans, corr, gc, gs, gw,
                                  hbf, WtopT, part, nodes, cover, Qa, Ka);
  k2_gat<<<BB, 1024, 0, stream>>>(part, nodes, spans, W1, a_src1, a_dst1, b1, ln_g, ln_b,
                                  W2, a_src2, a_dst2, b2, enhg);
  k2b_e2<<<dim3(CDIM / 256, BB), 256, 0, stream>>>(enhg, dense_W, E2);
  k3_dense<<<dim3(CDIM / 128, (BB * SS) / 128), 256, 0, stream>>>(hbf, WtopT, dense_b,
                                                                  cover, E2, Qa, Ka);
  k5_logits<<<dim3(8, 8, BB * TT), 256, 0, stream>>>(Qa, Ka, amask, outp);
}